// Round 1
// baseline (166.839 us; speedup 1.0000x reference)
//
#include <hip/hip_runtime.h>
#include <hip/hip_bf16.h>

// Per-edge dot product: score[e] = dot(x[src[e]], x[dst[e]]), D_FEAT = 128.
// x: [N_NODES,128] f32; src,dst: [E] int32 (JAX x64 disabled -> int32);
// out: [E] f32 (shape [E,1] flattened).
//
// Layout: 32 lanes per edge, one float4 (4 feats) per lane = 128 feats.
// Each 512B row is read as one fully-coalesced 32-lane x 16B group.
// Reduction: __shfl_xor butterfly with masks 16..1 stays inside each
// 32-lane half of the wave64, so one wave handles 2 independent edges.

__global__ __launch_bounds__(256) void edge_dot_kernel(
    const float* __restrict__ x,
    const int*   __restrict__ src,
    const int*   __restrict__ dst,
    float*       __restrict__ out,
    int n_edges) {
  const int gtid = blockIdx.x * blockDim.x + threadIdx.x;
  const int edge = gtid >> 5;        // 32 lanes per edge
  const int lane = threadIdx.x & 31; // lane within the edge's group
  if (edge >= n_edges) return;

  const size_t s = (size_t)(unsigned)src[edge];
  const size_t d = (size_t)(unsigned)dst[edge];

  const float4* __restrict__ xs =
      reinterpret_cast<const float4*>(x + s * 128);
  const float4* __restrict__ xd =
      reinterpret_cast<const float4*>(x + d * 128);

  const float4 a = xs[lane];
  const float4 b = xd[lane];

  float acc = a.x * b.x + a.y * b.y + a.z * b.z + a.w * b.w;

  // Butterfly reduce across the 32 lanes of this edge's group.
  #pragma unroll
  for (int m = 16; m > 0; m >>= 1)
    acc += __shfl_xor(acc, m, 64);

  if (lane == 0) out[edge] = acc;
}

extern "C" void kernel_launch(void* const* d_in, const int* in_sizes, int n_in,
                              void* d_out, int out_size, void* d_ws, size_t ws_size,
                              hipStream_t stream) {
  const float* x   = (const float*)d_in[0];
  const int*   src = (const int*)d_in[1];
  const int*   dst = (const int*)d_in[2];
  float*       out = (float*)d_out;

  const int n_edges = in_sizes[1];        // 1,200,000
  const int threads = 256;                // 8 edges per block
  const int edges_per_block = threads / 32;
  const int grid = (n_edges + edges_per_block - 1) / edges_per_block;

  edge_dot_kernel<<<grid, threads, 0, stream>>>(x, src, dst, out, n_edges);
}